// Round 1
// baseline (49.620 us; speedup 1.0000x reference)
//
#include <hip/hip_runtime.h>
#include <math.h>

// MoE gate: logits = x @ W^T (T=131072, D=512, E=4), fp32 softmax,
// top-2 of (softmax + bias), output gathered softmax weights + indices.
// Memory-bound: 256 MiB x-read dominates -> one wave per token, coalesced
// float4 loads, weights held in registers, shfl_xor butterfly reduction.

constexpr int TOKENS = 131072;
constexpr int DIM = 512;

__global__ __launch_bounds__(256) void gate_kernel(
    const float* __restrict__ x,      // [T, D]
    const float* __restrict__ w,      // [E, D]
    const float* __restrict__ bias,   // [E]
    float* __restrict__ out_w,        // [T, 2] fp32
    float* __restrict__ out_i)        // [T, 2] indices written as float
{
    const int lane   = threadIdx.x & 63;
    const int wavesPerBlock = blockDim.x >> 6;
    const int wave   = blockIdx.x * wavesPerBlock + (threadIdx.x >> 6);
    const int nwaves = gridDim.x * wavesPerBlock;

    // Preload this lane's slice of all 4 expert rows: w[e][lane*8 .. lane*8+7]
    float4 w0a, w0b, w1a, w1b, w2a, w2b, w3a, w3b;
    {
        const float4* wp0 = reinterpret_cast<const float4*>(w + 0 * DIM + lane * 8);
        const float4* wp1 = reinterpret_cast<const float4*>(w + 1 * DIM + lane * 8);
        const float4* wp2 = reinterpret_cast<const float4*>(w + 2 * DIM + lane * 8);
        const float4* wp3 = reinterpret_cast<const float4*>(w + 3 * DIM + lane * 8);
        w0a = wp0[0]; w0b = wp0[1];
        w1a = wp1[0]; w1b = wp1[1];
        w2a = wp2[0]; w2b = wp2[1];
        w3a = wp3[0]; w3b = wp3[1];
    }
    const float b0 = bias[0], b1 = bias[1], b2 = bias[2], b3 = bias[3];

    for (int t = wave; t < TOKENS; t += nwaves) {
        const float4* xp = reinterpret_cast<const float4*>(x + (size_t)t * DIM + lane * 8);
        const float4 xa = xp[0];
        const float4 xb = xp[1];

        float a0 = xa.x * w0a.x + xa.y * w0a.y + xa.z * w0a.z + xa.w * w0a.w
                 + xb.x * w0b.x + xb.y * w0b.y + xb.z * w0b.z + xb.w * w0b.w;
        float a1 = xa.x * w1a.x + xa.y * w1a.y + xa.z * w1a.z + xa.w * w1a.w
                 + xb.x * w1b.x + xb.y * w1b.y + xb.z * w1b.z + xb.w * w1b.w;
        float a2 = xa.x * w2a.x + xa.y * w2a.y + xa.z * w2a.z + xa.w * w2a.w
                 + xb.x * w2b.x + xb.y * w2b.y + xb.z * w2b.z + xb.w * w2b.w;
        float a3 = xa.x * w3a.x + xa.y * w3a.y + xa.z * w3a.z + xa.w * w3a.w
                 + xb.x * w3b.x + xb.y * w3b.y + xb.z * w3b.z + xb.w * w3b.w;

        // Butterfly reduction across the 64-lane wave; all lanes get full sums.
        #pragma unroll
        for (int off = 1; off < 64; off <<= 1) {
            a0 += __shfl_xor(a0, off, 64);
            a1 += __shfl_xor(a1, off, 64);
            a2 += __shfl_xor(a2, off, 64);
            a3 += __shfl_xor(a3, off, 64);
        }

        // fp32 softmax over 4 logits
        const float m  = fmaxf(fmaxf(a0, a1), fmaxf(a2, a3));
        const float e0 = __expf(a0 - m);
        const float e1 = __expf(a1 - m);
        const float e2 = __expf(a2 - m);
        const float e3 = __expf(a3 - m);
        const float inv = 1.0f / (e0 + e1 + e2 + e3);
        const float s0 = e0 * inv, s1 = e1 * inv, s2 = e2 * inv, s3 = e3 * inv;

        // biased scores for selection only
        const float p0 = s0 + b0, p1 = s1 + b1, p2 = s2 + b2, p3 = s3 + b3;

        // top-1 (strict > keeps lowest index on ties, matching lax.top_k)
        int   i0 = 0; float bv0 = p0, sv0 = s0;
        if (p1 > bv0) { bv0 = p1; sv0 = s1; i0 = 1; }
        if (p2 > bv0) { bv0 = p2; sv0 = s2; i0 = 2; }
        if (p3 > bv0) { bv0 = p3; sv0 = s3; i0 = 3; }
        // top-2: best among e != i0
        int   i1 = -1; float bv1 = -INFINITY, sv1 = 0.0f;
        if (i0 != 0 && p0 > bv1) { bv1 = p0; sv1 = s0; i1 = 0; }
        if (i0 != 1 && p1 > bv1) { bv1 = p1; sv1 = s1; i1 = 1; }
        if (i0 != 2 && p2 > bv1) { bv1 = p2; sv1 = s2; i1 = 2; }
        if (i0 != 3 && p3 > bv1) { bv1 = p3; sv1 = s3; i1 = 3; }

        if (lane == 0) {
            float2 wv = make_float2(sv0, sv1);                    // ROUTE_SCALE == 1.0
            float2 iv = make_float2((float)i0, (float)i1);
            *reinterpret_cast<float2*>(out_w + 2 * (size_t)t) = wv;
            *reinterpret_cast<float2*>(out_i + 2 * (size_t)t) = iv;
        }
    }
}

extern "C" void kernel_launch(void* const* d_in, const int* in_sizes, int n_in,
                              void* d_out, int out_size, void* d_ws, size_t ws_size,
                              hipStream_t stream) {
    const float* x    = (const float*)d_in[0];
    const float* w    = (const float*)d_in[1];
    const float* bias = (const float*)d_in[2];

    float* out_w = (float*)d_out;                    // [T,2] weights
    float* out_i = (float*)d_out + (size_t)TOKENS * 2; // [T,2] indices (as float)

    const int block  = 256;                 // 4 waves/block
    const int blocks = 2048;                // 8192 waves -> 16 tokens/wave
    gate_kernel<<<blocks, block, 0, stream>>>(x, w, bias, out_w, out_i);
}